// Round 12
// baseline (161.805 us; speedup 1.0000x reference)
//
#include <hip/hip_runtime.h>
#include <hip/hip_bf16.h>

// AdaDConv: B=8, C=256, H=W=128, K=3, S=2 -> oh=ow=64, k2=9
//   prep   : fold BN into conv weights -> wt[c][3][28] chunks (10 blocks);
//            bias[16]; gap=0
//   conv   : LDS-double-buffered: block = 4 output rows x 64 cols, one
//            channel at a time (32/block). Stage c+1's 9x128 panel into
//            xs[2][..] (2 float4/thread reg transit, write after FMA =
//            T14), FMA taps read from LDS (left tap = xs[r][2j-1], no
//            shfl). Per-thread state ~70 VGPR -> no spill (the R5/R7/R9
//            register-prefetch spills are structurally impossible here).
//            Gap fused into staging via LDS atomics. One sync/channel.
//   reduce : wlog = sum_z wlogp[z] + bias   (+ chnet in blocks 384..391)
//   final  : column-pair float4 loads; wlog in regs; softmax * reflect -> out

#define EPS 1e-5f
#define CH_SPLIT 8
#define WLOG_N 393216  // 8*64*64*12

__global__ __launch_bounds__(256) void prep_kernel(
    const float* __restrict__ wconv, const float* __restrict__ gamma,
    const float* __restrict__ beta, const float* __restrict__ mean,
    const float* __restrict__ var, float* __restrict__ wt,
    float* __restrict__ bias, float* __restrict__ gap) {
  const int blk = blockIdx.x;
  const int c = threadIdx.x;  // 0..255
  if (blk < 9) {
    const int t = blk;
    const float sc = gamma[t] * rsqrtf(var[t] + EPS);
    const float* src = wconv + ((size_t)t * 256 + c) * 9;
    float* dst = wt + c * 84;
    #pragma unroll
    for (int ki = 0; ki < 3; ++ki)
      #pragma unroll
      for (int kj = 0; kj < 3; ++kj)
        dst[ki * 28 + t * 3 + kj] = src[ki * 3 + kj] * sc;
  } else {
    #pragma unroll
    for (int ki = 0; ki < 3; ++ki) wt[c * 84 + ki * 28 + 27] = 0.f;
    #pragma unroll
    for (int k = 0; k < 8; ++k) gap[k * 256 + c] = 0.f;
    if (c < 9) bias[c] = beta[c] - mean[c] * gamma[c] * rsqrtf(var[c] + EPS);
    else if (c < 16) bias[c] = 0.f;
  }
}

// Block 256 = 4 waves. Wave ri = output row i0+ri, lane j = output col.
// 32 channels (z*32..+31) processed one at a time, x panel (9 rows x 128)
// LDS-double-buffered. Thread stages float4 f0=tid (+ f1=256+tid if tid<32).
// Rows 1..8 of each panel tile the image exactly once -> fused gap.
__global__ __launch_bounds__(256, 2) void conv_kernel(
    const float* __restrict__ x, const float* __restrict__ wt,
    float* __restrict__ wlogp, float* __restrict__ gap) {
  const int tid = threadIdx.x;
  const int j = tid & 63;
  const int ri = tid >> 6;  // wave id = output row offset 0..3
  const int i0 = blockIdx.x * 4;
  const int b = blockIdx.y;
  const int z = blockIdx.z;

  __shared__ float sw[2688];       // 32 ch * 84 weights
  __shared__ float xs[2][9][128];  // double-buffered x panel
  __shared__ float gap_lds[32];

  {  // cooperative weight stage: channels z*32 .. z*32+31 (672 float4s)
    const float4* src = (const float4*)(wt + (size_t)z * 32 * 84);
    float4* dst = (float4*)sw;
    #pragma unroll
    for (int k = 0; k < 3; ++k) {
      int idx = k * 256 + tid;
      if (idx < 672) dst[idx] = src[idx];
    }
  }
  if (tid < 32) gap_lds[tid] = 0.f;
  __syncthreads();

  const float* xb = x + ((size_t)b * 256 + (size_t)z * 32) * 16384;
  const int h0 = 2 * i0 - 1;

  // staging geometry (fixed per thread)
  const int rf0 = tid >> 5;  // row 0..7 of panel
  const int c40 = tid & 31;  // float4 col
  const int hh0 = h0 + rf0;
  const bool ok0 = (unsigned)hh0 < 128u;  // false only at i0==0, rf0==0
  const bool do1 = tid < 32;              // second float4: row 8
  const int hh1 = h0 + 8;                 // always in [0,127]

  float acc[9];
  #pragma unroll
  for (int t = 0; t < 9; ++t) acc[t] = 0.f;

  {  // prologue: stage channel 0 into xs[0]
    const float* xc = xb;
    float4 s0 = ok0 ? *(const float4*)(xc + hh0 * 128 + c40 * 4)
                    : make_float4(0.f, 0.f, 0.f, 0.f);
    float4 s1 = make_float4(0.f, 0.f, 0.f, 0.f);
    if (do1) s1 = *(const float4*)(xc + hh1 * 128 + c40 * 4);
    float gs = 0.f;
    if (rf0 >= 1) gs += (s0.x + s0.y) + (s0.z + s0.w);
    gs += (s1.x + s1.y) + (s1.z + s1.w);
    atomicAdd(&gap_lds[0], gs);
    float4* base = (float4*)&xs[0][0][0];
    base[tid] = s0;
    if (do1) base[256 + tid] = s1;
  }

  for (int c = 0; c < 32; ++c) {
    __syncthreads();  // xs[c&1] ready; also guards write to xs[(c+1)&1]
    const int bf = c & 1;

    // issue next channel's global loads (latency hides under the FMAs)
    float4 s0 = make_float4(0.f, 0.f, 0.f, 0.f);
    float4 s1 = make_float4(0.f, 0.f, 0.f, 0.f);
    const bool pf = (c < 31);
    if (pf) {
      const float* xc = xb + (size_t)(c + 1) * 16384;
      if (ok0) s0 = *(const float4*)(xc + hh0 * 128 + c40 * 4);
      if (do1) s1 = *(const float4*)(xc + hh1 * 128 + c40 * 4);
    }

    // FMA on current panel
    const float* wcb = sw + c * 84;
    #pragma unroll
    for (int ki = 0; ki < 3; ++ki) {
      float4 wk[7];
      const float4* wq = (const float4*)(wcb + ki * 28);
      #pragma unroll
      for (int p = 0; p < 7; ++p) wk[p] = wq[p];
      const float* w = (const float*)wk;  // w[t*3 + kj]
      const int r = 2 * ri + ki;
      const float2 v = *(const float2*)&xs[bf][r][2 * j];
      const float lf = (j == 0) ? 0.f : xs[bf][r][2 * j - 1];
      #pragma unroll
      for (int t = 0; t < 9; ++t) {
        float a = acc[t];
        a = fmaf(lf, w[t * 3 + 0], a);
        a = fmaf(v.x, w[t * 3 + 1], a);
        a = fmaf(v.y, w[t * 3 + 2], a);
        acc[t] = a;
      }
    }

    if (pf) {  // gap partial + LDS write of next panel
      float gs = 0.f;
      if (rf0 >= 1) gs += (s0.x + s0.y) + (s0.z + s0.w);
      gs += (s1.x + s1.y) + (s1.z + s1.w);
      atomicAdd(&gap_lds[c + 1], gs);
      float4* base = (float4*)&xs[bf ^ 1][0][0];
      base[tid] = s0;
      if (do1) base[256 + tid] = s1;
    }
  }

  __syncthreads();
  if (tid < 32) atomicAdd(&gap[b * 256 + z * 32 + tid], gap_lds[tid]);

  // direct store of this thread's output pixel row (12-float padded slot)
  {
    float* wzp = wlogp + (size_t)z * WLOG_N;
    const size_t pos = ((size_t)b * 64 + (i0 + ri)) * 64 + j;
    float4* wp = (float4*)(wzp + pos * 12);
    wp[0] = make_float4(acc[0], acc[1], acc[2], acc[3]);
    wp[1] = make_float4(acc[4], acc[5], acc[6], acc[7]);
    wp[2] = make_float4(acc[8], 0.f, 0.f, 0.f);
  }
}

// blocks 0..383: wlog[i] = sum_z wlogp[z][i] + bias[i%12]  (float4/thread)
// blocks 384..391: chnet for b = blk-384
__global__ __launch_bounds__(256) void reduce_chnet_kernel(
    const float* __restrict__ wlogp, const float* __restrict__ bias,
    float* __restrict__ wlog, const float* __restrict__ gap,
    const float* __restrict__ w1, const float* __restrict__ w2,
    float* __restrict__ ch) {
  __shared__ float g[256];
  __shared__ float h[64];
  const int blk = blockIdx.x;
  if (blk < 384) {
    const int i4 = blk * 256 + threadIdx.x;  // float4 index
    float4 s = make_float4(0.f, 0.f, 0.f, 0.f);
    #pragma unroll
    for (int zz = 0; zz < 8; ++zz) {
      float4 p = *(const float4*)(wlogp + (size_t)zz * WLOG_N + (size_t)i4 * 4);
      s.x += p.x; s.y += p.y; s.z += p.z; s.w += p.w;
    }
    const int base = i4 * 4;
    s.x += bias[(base + 0) % 12];
    s.y += bias[(base + 1) % 12];
    s.z += bias[(base + 2) % 12];
    s.w += bias[(base + 3) % 12];
    *(float4*)(wlog + base) = s;
  } else {
    const int b = blk - 384;
    const int t = threadIdx.x;
    g[t] = gap[b * 256 + t] * (1.f / 16384.f);
    __syncthreads();
    if (t < 64) {
      float s = 0.f;
      const float* w = w1 + t * 256;
      for (int c = 0; c < 256; ++c) s += g[c] * w[c];
      h[t] = fmaxf(s, 0.f);
    }
    __syncthreads();
    float s = 0.f;
    const float* w = w2 + t * 64;
    #pragma unroll 4
    for (int jj = 0; jj < 64; ++jj) s += h[jj] * w[jj];
    ch[b * 256 + t] = s;
  }
}

// Thread: output cols (2q, 2q+1) of row i, 8 channels. x via float4 (16B/lane);
// left tap from prev lane's .w (shfl width 32); q==0 reflect = own .y.
__global__ __launch_bounds__(256) void final_kernel(
    const float* __restrict__ x, const float* __restrict__ wlog,
    const float* __restrict__ ch, float* __restrict__ out) {
  const int q = threadIdx.x & 31;
  const int rw = threadIdx.x >> 5;   // 0..7
  const int i = blockIdx.x * 8 + rw; // out row
  const int b = blockIdx.y;
  const int c0 = blockIdx.z * 8;

  const size_t pos = ((size_t)b * 64 + i) * 64 + 2 * q;
  const float4* wp = (const float4*)(wlog + pos * 12);
  float4 w0 = wp[0], w1 = wp[1], w2 = wp[2];
  float4 w3 = wp[3], w4 = wp[4], w5 = wp[5];
  const float wlA[9] = {w0.x, w0.y, w0.z, w0.w, w1.x, w1.y, w1.z, w1.w, w2.x};
  const float wlB[9] = {w3.x, w3.y, w3.z, w3.w, w4.x, w4.y, w4.z, w4.w, w5.x};

  float mxA = wlA[0], mnA = wlA[0], mxB = wlB[0], mnB = wlB[0];
  #pragma unroll
  for (int t = 1; t < 9; ++t) {
    mxA = fmaxf(mxA, wlA[t]); mnA = fminf(mnA, wlA[t]);
    mxB = fmaxf(mxB, wlB[t]); mnB = fminf(mnB, wlB[t]);
  }

  const float* chp = ch + b * 256 + c0;
  const float* xp0 = x + ((size_t)b * 256 + c0) * 16384 + 4 * q;
  float* op = out + ((size_t)b * 256 + c0) * 4096 + i * 64 + 2 * q;

  const int hm = (i == 0) ? 1 : 2 * i - 1;  // reflect row -1 -> 1

  for (int c = 0; c < 8; ++c) {
    const float chv = chp[c];
    const float* xp = xp0 + (size_t)c * 16384;
    float4 v0 = *(const float4*)(xp + hm * 128);
    float4 v1 = *(const float4*)(xp + (2 * i) * 128);
    float4 v2 = *(const float4*)(xp + (2 * i + 1) * 128);

    float l0 = __shfl_up(v0.w, 1, 32);
    float l1 = __shfl_up(v1.w, 1, 32);
    float l2 = __shfl_up(v2.w, 1, 32);
    if (q == 0) { l0 = v0.y; l1 = v1.y; l2 = v2.y; }  // reflect col -1 -> 1

    // pixel A: out col 2q, taps {left, .x, .y} per row
    {
      const float m = fmaxf(mxA * chv, mnA * chv);
      float e[9], s = 0.f;
      #pragma unroll
      for (int t = 0; t < 9; ++t) {
        e[t] = __expf(wlA[t] * chv - m);
        s += e[t];
      }
      float acc = e[0] * l0 + e[1] * v0.x + e[2] * v0.y;
      acc += e[3] * l1 + e[4] * v1.x + e[5] * v1.y;
      acc += e[6] * l2 + e[7] * v2.x + e[8] * v2.y;
      op[(size_t)c * 4096] = acc / s;
    }
    // pixel B: out col 2q+1, taps {.y, .z, .w} per row
    {
      const float m = fmaxf(mxB * chv, mnB * chv);
      float e[9], s = 0.f;
      #pragma unroll
      for (int t = 0; t < 9; ++t) {
        e[t] = __expf(wlB[t] * chv - m);
        s += e[t];
      }
      float acc = e[0] * v0.y + e[1] * v0.z + e[2] * v0.w;
      acc += e[3] * v1.y + e[4] * v1.z + e[5] * v1.w;
      acc += e[6] * v2.y + e[7] * v2.z + e[8] * v2.w;
      op[(size_t)c * 4096 + 1] = acc / s;
    }
  }
}

extern "C" void kernel_launch(void* const* d_in, const int* in_sizes, int n_in,
                              void* d_out, int out_size, void* d_ws,
                              size_t ws_size, hipStream_t stream) {
  const float* x = (const float*)d_in[0];
  const float* w_conv = (const float*)d_in[1];
  const float* bn_gamma = (const float*)d_in[2];
  const float* bn_beta = (const float*)d_in[3];
  const float* bn_mean = (const float*)d_in[4];
  const float* bn_var = (const float*)d_in[5];
  const float* ch_w1 = (const float*)d_in[6];
  const float* ch_w2 = (const float*)d_in[7];
  float* out = (float*)d_out;

  float* wsf = (float*)d_ws;
  float* gap = wsf;            // 2048
  float* ch = wsf + 2048;      // 2048
  float* bias = wsf + 4096;    // 16
  float* wt = wsf + 4112;      // 256*84 = 21504
  float* wlog = wsf + 25616;   // 393216
  float* wlogp = wsf + 418832; // 8*393216 = 3145728

  prep_kernel<<<10, 256, 0, stream>>>(w_conv, bn_gamma, bn_beta, bn_mean,
                                      bn_var, wt, bias, gap);
  conv_kernel<<<dim3(16, 8, CH_SPLIT), 256, 0, stream>>>(x, wt, wlogp, gap);
  reduce_chnet_kernel<<<392, 256, 0, stream>>>(wlogp, bias, wlog, gap, ch_w1,
                                               ch_w2, ch);
  final_kernel<<<dim3(8, 8, 32), 256, 0, stream>>>(x, wlog, ch, out);
}

// Round 13
// 88.184 us; speedup vs baseline: 1.8349x; 1.8349x over previous
//
#include <hip/hip_runtime.h>
#include <hip/hip_bf16.h>

// AdaDConv: B=8, C=256, H=W=128, K=3, S=2 -> oh=ow=64, k2=9
//   prep   : fold BN into conv weights -> wt[c][3][28] chunks (10 blocks);
//            bias[16]; gap=0
//   conv   : x -> wlogp[z] partials + fused gap. 4-row tile/block, 8 ch/wave.
//            WEIGHTS VIA SCALAR PATH: uniform (readfirstlane) pointer into
//            global wt -> compiler s_load into SGPRs; no LDS staging, no
//            per-channel ds_read_b128 storm (R4..R11 all oversubscribed the
//            LDS port: 21 b128/ch/wave ~ 4000cy/CU-phase vs 2600cy FMA).
//            X via float4 col-pairs: lane q owns output cols 2q,2q+1 ->
//            10 VMEM/channel (was 18), 16B coalesced. Live ~80 VGPR,
//            (256,2) cap 128 (proven safe, rounds 8 vs 5/7/9).
//   reduce : wlog = sum_z wlogp[z] + bias   (+ chnet in blocks 384..391)
//   final  : column-pair float4 loads; wlog in regs; softmax * reflect -> out

#define EPS 1e-5f
#define CH_SPLIT 8
#define WLOG_N 393216  // 8*64*64*12

__global__ __launch_bounds__(256) void prep_kernel(
    const float* __restrict__ wconv, const float* __restrict__ gamma,
    const float* __restrict__ beta, const float* __restrict__ mean,
    const float* __restrict__ var, float* __restrict__ wt,
    float* __restrict__ bias, float* __restrict__ gap) {
  const int blk = blockIdx.x;
  const int c = threadIdx.x;  // 0..255
  if (blk < 9) {
    const int t = blk;
    const float sc = gamma[t] * rsqrtf(var[t] + EPS);
    const float* src = wconv + ((size_t)t * 256 + c) * 9;
    float* dst = wt + c * 84;
    #pragma unroll
    for (int ki = 0; ki < 3; ++ki)
      #pragma unroll
      for (int kj = 0; kj < 3; ++kj)
        dst[ki * 28 + t * 3 + kj] = src[ki * 3 + kj] * sc;
  } else {
    #pragma unroll
    for (int ki = 0; ki < 3; ++ki) wt[c * 84 + ki * 28 + 27] = 0.f;
    #pragma unroll
    for (int k = 0; k < 8; ++k) gap[k * 256 + c] = 0.f;
    if (c < 9) bias[c] = beta[c] - mean[c] * gamma[c] * rsqrtf(var[c] + EPS);
    else if (c < 16) bias[c] = 0.f;
  }
}

// Block 256 = 4 waves; wave wv owns channels [z*32+wv*8, +8), block covers
// output rows i0..i0+3, cols 0..63. Lane l: q=l&31 -> output cols 2q,2q+1;
// sh=l>>5 -> row pair (i0+2sh, i0+2sh+1). Per channel: 5 float4 + 5 scalar
// left-tap loads; 324 FMAs with SGPR weights. Input rows 2*ip0..2*ip0+3 per
// lane tile the image exactly once -> fused gap sum.
__global__ __launch_bounds__(256, 2) void conv_kernel(
    const float* __restrict__ x, const float* __restrict__ wt,
    float* __restrict__ wlogp, float* __restrict__ gap) {
  const int tid = threadIdx.x;
  const int l = tid & 63;
  const int q = l & 31;
  const int sh = l >> 5;
  const int wv = tid >> 6;  // 0..3
  const int i0 = blockIdx.x * 4;
  const int b = blockIdx.y;
  const int z = blockIdx.z;

  __shared__ float red[4][64][9];  // 9216 B (only LDS in this kernel)

  float acc[2][2][9];  // [ro][cp][t]
  #pragma unroll
  for (int ro = 0; ro < 2; ++ro)
    #pragma unroll
    for (int cp = 0; cp < 2; ++cp)
      #pragma unroll
      for (int t = 0; t < 9; ++t) acc[ro][cp][t] = 0.f;

  const int cbase = __builtin_amdgcn_readfirstlane(z * 32 + wv * 8);
  const float* xb = x + ((size_t)b * 256 + cbase) * 16384;
  const float* wb = wt + (size_t)cbase * 84;  // uniform -> scalar loads
  const int ip0 = i0 + 2 * sh;                // lane's first output row
  const int h0 = 2 * ip0 - 1;                 // input row base; -1 only at top
  const int jl = (q == 0) ? 0 : (4 * q - 1);  // clamped left-tap col

  for (int c = 0; c < 8; ++c) {
    const float* xc = xb + (size_t)c * 16384;
    float4 v[5];
    float lf[5];
    #pragma unroll
    for (int r = 0; r < 5; ++r) {
      const int hh = h0 + r;
      if ((unsigned)hh < 128u) {
        v[r] = *(const float4*)(xc + hh * 128 + 4 * q);
        lf[r] = xc[hh * 128 + jl];
      } else {
        v[r] = make_float4(0.f, 0.f, 0.f, 0.f);
        lf[r] = 0.f;
      }
    }
    if (q == 0) {
      #pragma unroll
      for (int r = 0; r < 5; ++r) lf[r] = 0.f;  // conv zero-pad col -1
    }

    // fused gap: input rows r=1..4 (= 2*ip0 .. 2*ip0+3) owned exactly once
    {
      float gs = 0.f;
      #pragma unroll
      for (int r = 1; r < 5; ++r)
        gs += (v[r].x + v[r].y) + (v[r].z + v[r].w);
      #pragma unroll
      for (int off = 32; off; off >>= 1) gs += __shfl_xor(gs, off, 64);
      if (l == 0) atomicAdd(&gap[b * 256 + cbase + c], gs);
    }

    const float* wc = wb + c * 84;  // uniform
    #pragma unroll
    for (int ki = 0; ki < 3; ++ki) {
      const float* w = wc + ki * 28;  // w[t*3 + kj], uniform -> s_load
      #pragma unroll
      for (int ro = 0; ro < 2; ++ro) {
        const int r = 2 * ro + ki;
        const float xA0 = lf[r], xA1 = v[r].x, xA2 = v[r].y;
        const float xB1 = v[r].z, xB2 = v[r].w;
        #pragma unroll
        for (int t = 0; t < 9; ++t) {
          const float w0 = w[t * 3 + 0], w1 = w[t * 3 + 1], w2 = w[t * 3 + 2];
          float a = acc[ro][0][t];
          a = fmaf(xA0, w0, a);
          a = fmaf(xA1, w1, a);
          a = fmaf(xA2, w2, a);
          acc[ro][0][t] = a;
          float bacc = acc[ro][1][t];
          bacc = fmaf(xA2, w0, bacc);
          bacc = fmaf(xB1, w1, bacc);
          bacc = fmaf(xB2, w2, bacc);
          acc[ro][1][t] = bacc;
        }
      }
    }
  }

  // 4-wave combine + store, one output row per phase (R8-proven epilogue)
  float* wzp = wlogp + (size_t)z * WLOG_N;
  #pragma unroll
  for (int ri = 0; ri < 4; ++ri) {
    __syncthreads();
    if (sh == (ri >> 1)) {
      const int ro = ri & 1;
      #pragma unroll
      for (int t = 0; t < 9; ++t) {
        red[wv][2 * q + 0][t] = acc[ro][0][t];
        red[wv][2 * q + 1][t] = acc[ro][1][t];
      }
    }
    __syncthreads();
    const size_t rowpos = ((size_t)b * 64 + (i0 + ri)) * 64;
    float* wp = wzp + rowpos * 12;
    for (int idx = tid; idx < 768; idx += 256) {
      const int jj = idx / 12, tt = idx - jj * 12;
      float s = 0.f;
      if (tt < 9)
        s = red[0][jj][tt] + red[1][jj][tt] + red[2][jj][tt] + red[3][jj][tt];
      wp[idx] = s;  // coalesced; pad slots get 0
    }
  }
}

// blocks 0..383: wlog[i] = sum_z wlogp[z][i] + bias[i%12]  (float4/thread)
// blocks 384..391: chnet for b = blk-384
__global__ __launch_bounds__(256) void reduce_chnet_kernel(
    const float* __restrict__ wlogp, const float* __restrict__ bias,
    float* __restrict__ wlog, const float* __restrict__ gap,
    const float* __restrict__ w1, const float* __restrict__ w2,
    float* __restrict__ ch) {
  __shared__ float g[256];
  __shared__ float h[64];
  const int blk = blockIdx.x;
  if (blk < 384) {
    const int i4 = blk * 256 + threadIdx.x;  // float4 index
    float4 s = make_float4(0.f, 0.f, 0.f, 0.f);
    #pragma unroll
    for (int zz = 0; zz < 8; ++zz) {
      float4 p = *(const float4*)(wlogp + (size_t)zz * WLOG_N + (size_t)i4 * 4);
      s.x += p.x; s.y += p.y; s.z += p.z; s.w += p.w;
    }
    const int base = i4 * 4;
    s.x += bias[(base + 0) % 12];
    s.y += bias[(base + 1) % 12];
    s.z += bias[(base + 2) % 12];
    s.w += bias[(base + 3) % 12];
    *(float4*)(wlog + base) = s;
  } else {
    const int b = blk - 384;
    const int t = threadIdx.x;
    g[t] = gap[b * 256 + t] * (1.f / 16384.f);
    __syncthreads();
    if (t < 64) {
      float s = 0.f;
      const float* w = w1 + t * 256;
      for (int c = 0; c < 256; ++c) s += g[c] * w[c];
      h[t] = fmaxf(s, 0.f);
    }
    __syncthreads();
    float s = 0.f;
    const float* w = w2 + t * 64;
    #pragma unroll 4
    for (int jj = 0; jj < 64; ++jj) s += h[jj] * w[jj];
    ch[b * 256 + t] = s;
  }
}

// Thread: output cols (2q, 2q+1) of row i, 8 channels. x via float4 (16B/lane);
// left tap from prev lane's .w (shfl width 32); q==0 reflect = own .y.
__global__ __launch_bounds__(256) void final_kernel(
    const float* __restrict__ x, const float* __restrict__ wlog,
    const float* __restrict__ ch, float* __restrict__ out) {
  const int q = threadIdx.x & 31;
  const int rw = threadIdx.x >> 5;   // 0..7
  const int i = blockIdx.x * 8 + rw; // out row
  const int b = blockIdx.y;
  const int c0 = blockIdx.z * 8;

  const size_t pos = ((size_t)b * 64 + i) * 64 + 2 * q;
  const float4* wp = (const float4*)(wlog + pos * 12);
  float4 w0 = wp[0], w1 = wp[1], w2 = wp[2];
  float4 w3 = wp[3], w4 = wp[4], w5 = wp[5];
  const float wlA[9] = {w0.x, w0.y, w0.z, w0.w, w1.x, w1.y, w1.z, w1.w, w2.x};
  const float wlB[9] = {w3.x, w3.y, w3.z, w3.w, w4.x, w4.y, w4.z, w4.w, w5.x};

  float mxA = wlA[0], mnA = wlA[0], mxB = wlB[0], mnB = wlB[0];
  #pragma unroll
  for (int t = 1; t < 9; ++t) {
    mxA = fmaxf(mxA, wlA[t]); mnA = fminf(mnA, wlA[t]);
    mxB = fmaxf(mxB, wlB[t]); mnB = fminf(mnB, wlB[t]);
  }

  const float* chp = ch + b * 256 + c0;
  const float* xp0 = x + ((size_t)b * 256 + c0) * 16384 + 4 * q;
  float* op = out + ((size_t)b * 256 + c0) * 4096 + i * 64 + 2 * q;

  const int hm = (i == 0) ? 1 : 2 * i - 1;  // reflect row -1 -> 1

  for (int c = 0; c < 8; ++c) {
    const float chv = chp[c];
    const float* xp = xp0 + (size_t)c * 16384;
    float4 v0 = *(const float4*)(xp + hm * 128);
    float4 v1 = *(const float4*)(xp + (2 * i) * 128);
    float4 v2 = *(const float4*)(xp + (2 * i + 1) * 128);

    float l0 = __shfl_up(v0.w, 1, 32);
    float l1 = __shfl_up(v1.w, 1, 32);
    float l2 = __shfl_up(v2.w, 1, 32);
    if (q == 0) { l0 = v0.y; l1 = v1.y; l2 = v2.y; }  // reflect col -1 -> 1

    // pixel A: out col 2q, taps {left, .x, .y} per row
    {
      const float m = fmaxf(mxA * chv, mnA * chv);
      float e[9], s = 0.f;
      #pragma unroll
      for (int t = 0; t < 9; ++t) {
        e[t] = __expf(wlA[t] * chv - m);
        s += e[t];
      }
      float acc = e[0] * l0 + e[1] * v0.x + e[2] * v0.y;
      acc += e[3] * l1 + e[4] * v1.x + e[5] * v1.y;
      acc += e[6] * l2 + e[7] * v2.x + e[8] * v2.y;
      op[(size_t)c * 4096] = acc / s;
    }
    // pixel B: out col 2q+1, taps {.y, .z, .w} per row
    {
      const float m = fmaxf(mxB * chv, mnB * chv);
      float e[9], s = 0.f;
      #pragma unroll
      for (int t = 0; t < 9; ++t) {
        e[t] = __expf(wlB[t] * chv - m);
        s += e[t];
      }
      float acc = e[0] * v0.y + e[1] * v0.z + e[2] * v0.w;
      acc += e[3] * v1.y + e[4] * v1.z + e[5] * v1.w;
      acc += e[6] * v2.y + e[7] * v2.z + e[8] * v2.w;
      op[(size_t)c * 4096 + 1] = acc / s;
    }
  }
}

extern "C" void kernel_launch(void* const* d_in, const int* in_sizes, int n_in,
                              void* d_out, int out_size, void* d_ws,
                              size_t ws_size, hipStream_t stream) {
  const float* x = (const float*)d_in[0];
  const float* w_conv = (const float*)d_in[1];
  const float* bn_gamma = (const float*)d_in[2];
  const float* bn_beta = (const float*)d_in[3];
  const float* bn_mean = (const float*)d_in[4];
  const float* bn_var = (const float*)d_in[5];
  const float* ch_w1 = (const float*)d_in[6];
  const float* ch_w2 = (const float*)d_in[7];
  float* out = (float*)d_out;

  float* wsf = (float*)d_ws;
  float* gap = wsf;            // 2048
  float* ch = wsf + 2048;      // 2048
  float* bias = wsf + 4096;    // 16
  float* wt = wsf + 4112;      // 256*84 = 21504
  float* wlog = wsf + 25616;   // 393216
  float* wlogp = wsf + 418832; // 8*393216 = 3145728

  prep_kernel<<<10, 256, 0, stream>>>(w_conv, bn_gamma, bn_beta, bn_mean,
                                      bn_var, wt, bias, gap);
  conv_kernel<<<dim3(16, 8, CH_SPLIT), 256, 0, stream>>>(x, wt, wlogp, gap);
  reduce_chnet_kernel<<<392, 256, 0, stream>>>(wlogp, bias, wlog, gap, ch_w1,
                                               ch_w2, ch);
  final_kernel<<<dim3(8, 8, 32), 256, 0, stream>>>(x, wlog, ch, out);
}